// Round 9
// baseline (175.050 us; speedup 1.0000x reference)
//
#include <hip/hip_runtime.h>
#include <math.h>

#define N_NODES 50000
#define N_EDGES 1600000
#define IN_CH 32
#define HID 64

// ---------------- pipeline (5 dispatches) ----------------------------------
// prep(wprep+xconv+zero) -> partition(both dirs/chunk, atomic slab reserve)
//   -> bindeg(+row-scale) -> fgather -> dense(MFMA)
// Round-24: R23's fgather+dense fusion regressed (168.8 -> 173.2): the
// gather phase is latency/TLP-bound and the fusion cut its residency from
// 7 to 4 blocks/CU to save a ~7us dense kernel. De-fused back to the R22
// forms. KEPT from R23: the both-dirs-per-chunk partition (CHUNK 4096,
// edges held in registers across both dir passes -- ei/ew read once,
// -9.6MB HBM).
#define NBIN 782
#define BIN_SHIFT 6
#define CHUNK 4096
#define NCHK ((N_EDGES + CHUNK - 1) / CHUNK)   // 391
#define FG_CAP 2560   // bin capacity: mean 2046 + ~11 sigma (Binomial)

#define PREP_WPREP_BLOCKS 48
#define PREP_XCONV_BLOCKS ((N_NODES * 8 + 255) / 256)  // 1563
#define PREP_BLOCKS (PREP_WPREP_BLOCKS + PREP_XCONV_BLOCKS + 1)  // 1612 (last zeroes binTot)

// ---------------- workspace layout (int element offsets into d_ws)
#define WS_WBF      0          // 6144 i = 12288 ushort (bf16 weights, B-frag order)
#define WS_BINTOT   6144       // 1568 i (per-(dir,bin) totals; atomic counters)
#define WS_BINCNT   7712       // 100096 i (1564 bins x 64 per-node counts)
#define WS_XSB      107808     // 800000 i = 1.6M ushort (bf16 x, unscaled)
#define WS_TXO      907808     // 800000 i (bf16 Tx_o, 50000 x 32)
#define WS_TXI      1707808    // 800000 i (bf16 Tx_i)
#define WS_XSO      2507808    // 800000 i (bf16 x*rdeg_out rows)
#define WS_XSI      3307808    // 800000 i (bf16 x*rdeg_in rows)
#define WS_BINNED   4107808    // int2[1564*2560] = 8007680 i (fixed slabs)
#define WS_END      12115488   // 48.5 MB (ws is 256 MiB)

typedef __attribute__((ext_vector_type(8))) short bf16x8;
typedef __attribute__((ext_vector_type(4))) float f32x4;

__device__ __forceinline__ unsigned short f2bf(float f) {  // RNE fp32 -> bf16
    unsigned int u = __float_as_uint(f);
    return (unsigned short)((u + 0x7fffu + ((u >> 16) & 1u)) >> 16);
}
__device__ __forceinline__ float bf2f(unsigned short b) {
    return __uint_as_float((unsigned int)b << 16);
}
// bf16-pair extraction from a packed 32-bit word (two channels)
__device__ __forceinline__ float bflo(int u) {
    return __uint_as_float(((unsigned int)u) << 16);
}
__device__ __forceinline__ float bfhi(int u) {
    return __uint_as_float(((unsigned int)u) & 0xffff0000u);
}

// 0. fused prep: block-role split.
//   blocks [0, 48)      : weight prep (bf16, B-fragment order)
//   blocks [48, 48+1563): x -> bf16 copy
//   block  1611         : zero binTot counters
// B-frag order: idx = ((kk*8+bn)*64+lane)*8+j holds
// Bmat[k=kk*32+(lane>>4)*8+j][n=bn*16+(lane&15)], Bmat = [Wz_eff | Wh_eff].
__global__ __launch_bounds__(256) void prep_kernel(
    const float* __restrict__ Wz, const float* __restrict__ Wh,
    const float4* __restrict__ x4, unsigned short* __restrict__ wbf,
    ushort4* __restrict__ xsb, int* __restrict__ binTot) {
    int tid = threadIdx.x;
    int b = blockIdx.x;
    if (b < PREP_WPREP_BLOCKS) {  // wprep role
        int idx = b * 256 + tid;
        if (idx >= 12288) return;
        int j = idx & 7, ln = (idx >> 3) & 63, bn = (idx >> 9) & 7, kk = idx >> 12;
        int k = kk * 32 + (ln >> 4) * 8 + j;
        int n = bn * 16 + (ln & 15);
        int slab = k >> 5, c = k & 31;
        const float* W = (n < 64) ? Wz : Wh;
        int o = n & 63;
        float v;
        if (slab == 0)      v = W[c * 64 + o] + W[(2 * 96 + c) * 64 + o];
        else if (slab == 1) v = W[(96 + c) * 64 + o];
        else                v = W[(3 * 96 + c) * 64 + o];
        wbf[idx] = f2bf(v);
    } else if (b < PREP_WPREP_BLOCKS + PREP_XCONV_BLOCKS) {  // xconv role
        int i = (b - PREP_WPREP_BLOCKS) * 256 + tid;
        if (i >= N_NODES * 8) return;
        float4 v = x4[i];
        ushort4 o;
        o.x = f2bf(v.x); o.y = f2bf(v.y); o.z = f2bf(v.z); o.w = f2bf(v.w);
        xsb[i] = o;
    } else {  // zero role (binTot atomic counters)
        for (int i = tid; i < 1568; i += 256) binTot[i] = 0;
    }
}

// 1. COALESCED partition, BOTH dirs per chunk. One block = one 4096-edge
// chunk; edges held in registers across both dir passes, so ei/ew are read
// exactly once. Per dir: LDS hist + rank -> one global atomicAdd per
// nonzero bin reserves a range in the bin's fixed slab (bin*FG_CAP); LDS
// re-staging keeps global write-out coalesced.
// Payload: bin[31:22] | dstLocal[21:16] | src[15:0] (bin stripped at write).
__global__ __launch_bounds__(512) void partition_kernel(
    const int* __restrict__ ei, const float* __restrict__ ew,
    int* __restrict__ binTot, int2* __restrict__ binned) {
    __shared__ int2 stg[CHUNK];      // 32 KB
    __shared__ int hist[NBIN];
    __shared__ int lst[NBIN];        // local bin starts (staging)
    __shared__ int gBase[NBIN];      // global base within slab (atomic)
    __shared__ int sc[512];
    int tid = threadIdx.x;
    int chunk = blockIdx.x;

    int e0 = chunk * CHUNK;
    int n_e = min(CHUNK, N_EDGES - e0);
    int rr[8], cc[8];
    float wwv[8];
#pragma unroll
    for (int j = 0; j < 8; ++j) {
        int idx = tid + j * 512;
        if (idx < n_e) {
            int e = e0 + idx;
            rr[j] = ei[e];
            cc[j] = ei[N_EDGES + e];
            wwv[j] = ew[e];
        } else {
            rr[j] = -1;
        }
    }

    for (int dir = 0; dir < 2; ++dir) {
        for (int i = tid; i < NBIN; i += 512) hist[i] = 0;
        __syncthreads();
        int binv[8], rankv[8];
        int2 pay[8];
#pragma unroll
        for (int j = 0; j < 8; ++j) {
            if (rr[j] >= 0) {
                int dst = dir ? rr[j] : cc[j];
                int src = dir ? cc[j] : rr[j];
                int b = dst >> BIN_SHIFT;
                binv[j] = b;
                rankv[j] = atomicAdd(&hist[b], 1);
                pay[j] = make_int2(
                    (int)(((unsigned)b << 22) | ((unsigned)(dst & 63) << 16) |
                          (unsigned)src),
                    __float_as_int(wwv[j]));
            } else {
                binv[j] = -1;
            }
        }
        __syncthreads();
        // pair-scan: 391 pairs cover 782 bins (staging offsets only)
        int ps = (tid < 391) ? (hist[2 * tid] + hist[2 * tid + 1]) : 0;
        sc[tid] = ps;
        __syncthreads();
        for (int off = 1; off < 512; off <<= 1) {
            int u = (tid >= off) ? sc[tid - off] : 0;
            __syncthreads();
            sc[tid] += u;
            __syncthreads();
        }
        if (tid < 391) {
            int pref = sc[tid] - ps;  // exclusive pair prefix
            lst[2 * tid] = pref;
            lst[2 * tid + 1] = pref + hist[2 * tid];
        }
        // reserve global ranges: one atomicAdd per nonzero bin
        for (int i = tid; i < NBIN; i += 512)
            gBase[i] = (hist[i] > 0) ? atomicAdd(&binTot[dir * NBIN + i], hist[i]) : 0;
        __syncthreads();
#pragma unroll
        for (int j = 0; j < 8; ++j)
            if (binv[j] >= 0) stg[lst[binv[j]] + rankv[j]] = pay[j];
        __syncthreads();
        for (int p = tid; p < n_e; p += 512) {
            int2 v2 = stg[p];
            int b = (int)(((unsigned)v2.x) >> 22);
            int off = gBase[b] + (p - lst[b]);
            if (off < FG_CAP)
                binned[(dir * NBIN + b) * FG_CAP + off] =
                    make_int2(v2.x & 0x3FFFFF, v2.y);
        }
        __syncthreads();  // protect lst/gBase/stg before next dir overwrites
    }
}

// 2. per-bin degrees + per-node counts + ROW SCALING.
// dir1 block computes rdeg_out for its 64 nodes -> writes xs_o = bf16(x *
// rdeg_out); dir0 block computes rdeg_in -> xs_i. Coalesced 8KB read + 4KB
// write per block. Bin slabs are fixed-stride (b*FG_CAP, count binTot[b]).
__global__ __launch_bounds__(256) void bindeg_kernel(
    const int* __restrict__ binTot, const int2* __restrict__ binned,
    const float4* __restrict__ x4, int* __restrict__ binCnt,
    ushort4* __restrict__ xso, ushort4* __restrict__ xsi) {
    __shared__ float wsum[64];
    __shared__ int cnt[64];
    int tid = threadIdx.x;
    int b = blockIdx.x;
    int dir = (b >= NBIN) ? 1 : 0;
    if (tid < 64) { wsum[tid] = 0.f; cnt[tid] = 0; }
    __syncthreads();
    int lo = b * FG_CAP;
    int n_e = min(binTot[b], FG_CAP);
    for (int p = tid; p < n_e; p += 256) {
        int2 v = binned[lo + p];
        int d = v.x >> 16;  // dstLocal (6 bits; bin bits stripped by partition)
        atomicAdd(&cnt[d], 1);
        atomicAdd(&wsum[d], __int_as_float(v.y));
    }
    __syncthreads();
    if (tid < 64) {
        binCnt[b * 64 + tid] = cnt[tid];
        float s = wsum[tid];
        wsum[tid] = (s != 0.f) ? (1.f / s) : 0.f;  // reuse slot: reciprocal
    }
    __syncthreads();
    // row scaling: 64 nodes x 8 float4 = 512 elements, 2 per thread
    ushort4* xsd = dir ? xso : xsi;  // dir1: rdeg_out -> xs_o; dir0: -> xs_i
    int node0 = (b - dir * NBIN) * 64;
#pragma unroll
    for (int i = tid; i < 512; i += 256) {
        int nl = i >> 3, q = i & 7;
        int node = node0 + nl;
        if (node < N_NODES) {
            float4 v = x4[node * 8 + q];
            float r = wsum[nl];
            ushort4 o;
            o.x = f2bf(v.x * r); o.y = f2bf(v.y * r);
            o.z = f2bf(v.z * r); o.w = f2bf(v.w * r);
            xsd[node * 8 + q] = o;
        }
    }
}

// 3. fused in-LDS binsort + register gather, both dirs, 256-thr blocks.
// B: 8-deep batched coalesced slab loads; atomic-rank; scatter (src, w).
// C: 64 groups x 4 lanes, int4 (16B, 8ch) gathers from PRE-SCALED rows.
__global__ __launch_bounds__(256, 7) void fgather_kernel(
    const int4* __restrict__ xso4, const int4* __restrict__ xsi4,
    const int* __restrict__ binTot, const int* __restrict__ binCnt,
    const int2* __restrict__ binned, float* __restrict__ ws_f) {
    __shared__ int2 s_edge[FG_CAP];  // 20.5 KB -> 7 blocks/CU
    __shared__ int s_off[65];
    __shared__ int s_cur[64];
    __shared__ int sc[64];
    int tid = threadIdx.x;
    int b = blockIdx.x;
    int dir = (b >= NBIN) ? 1 : 0;
    int bin = b - dir * NBIN;

    // A: exclusive scan of 64 counts
    int v = (tid < 64) ? binCnt[b * 64 + tid] : 0;
    if (tid < 64) sc[tid] = v;
    __syncthreads();
    for (int off = 1; off < 64; off <<= 1) {
        int u = (tid < 64 && tid >= off) ? sc[tid - off] : 0;
        __syncthreads();
        if (tid < 64) sc[tid] += u;
        __syncthreads();
    }
    if (tid < 64) {
        s_off[tid] = sc[tid] - v;
        s_cur[tid] = sc[tid] - v;
    }
    if (tid == 63) s_off[64] = sc[63];
    __syncthreads();

    // B: stream slab edges (8-deep batched); atomic-rank; scatter (src, w)
    int n_e = min(binTot[b], FG_CAP);
    const int2* bb = binned + b * FG_CAP;
    for (int base = 0; base < n_e; base += 2048) {
        int2 ev[8];
#pragma unroll
        for (int j = 0; j < 8; ++j) {
            int idx = base + j * 256 + tid;
            if (idx < n_e) ev[j] = bb[idx];
        }
#pragma unroll
        for (int j = 0; j < 8; ++j) {
            int idx = base + j * 256 + tid;
            if (idx < n_e) {
                int rk = atomicAdd(&s_cur[ev[j].x >> 16], 1);
                if (rk < FG_CAP)
                    s_edge[rk] = make_int2(ev[j].x & 0xffff, ev[j].y);
            }
        }
    }
    __syncthreads();

    // C: register-accumulating gather, 4 lanes/node, 16B loads, 4-way unrolled
    const int4* xsrc = dir ? xsi4 : xso4;  // dir0 uses x*rdeg_out rows
    int4* outp = (int4*)(ws_f + (dir == 0 ? WS_TXO : WS_TXI));
    int lane = tid & 3;        // which int4 (8 channels) of the 32-ch row
    int nl = tid >> 2;         // node-local index 0..63 (all nodes in one pass)
    int p = s_off[nl], end = s_off[nl + 1];
    float acc[8];
#pragma unroll
    for (int j = 0; j < 8; ++j) acc[j] = 0.f;
    for (; p + 3 < end; p += 4) {
        int2 v0 = s_edge[p], v1 = s_edge[p + 1];
        int2 v2 = s_edge[p + 2], v3 = s_edge[p + 3];
        int4 a0 = xsrc[v0.x * 4 + lane];
        int4 a1 = xsrc[v1.x * 4 + lane];
        int4 a2 = xsrc[v2.x * 4 + lane];
        int4 a3 = xsrc[v3.x * 4 + lane];
        float c0 = __int_as_float(v0.y), c1 = __int_as_float(v1.y);
        float c2 = __int_as_float(v2.y), c3 = __int_as_float(v3.y);
        acc[0] += c0 * bflo(a0.x) + c1 * bflo(a1.x) + c2 * bflo(a2.x) + c3 * bflo(a3.x);
        acc[1] += c0 * bfhi(a0.x) + c1 * bfhi(a1.x) + c2 * bfhi(a2.x) + c3 * bfhi(a3.x);
        acc[2] += c0 * bflo(a0.y) + c1 * bflo(a1.y) + c2 * bflo(a2.y) + c3 * bflo(a3.y);
        acc[3] += c0 * bfhi(a0.y) + c1 * bfhi(a1.y) + c2 * bfhi(a2.y) + c3 * bfhi(a3.y);
        acc[4] += c0 * bflo(a0.z) + c1 * bflo(a1.z) + c2 * bflo(a2.z) + c3 * bflo(a3.z);
        acc[5] += c0 * bfhi(a0.z) + c1 * bfhi(a1.z) + c2 * bfhi(a2.z) + c3 * bfhi(a3.z);
        acc[6] += c0 * bflo(a0.w) + c1 * bflo(a1.w) + c2 * bflo(a2.w) + c3 * bflo(a3.w);
        acc[7] += c0 * bfhi(a0.w) + c1 * bfhi(a1.w) + c2 * bfhi(a2.w) + c3 * bfhi(a3.w);
    }
    for (; p < end; ++p) {
        int2 v0 = s_edge[p];
        float c0 = __int_as_float(v0.y);
        int4 a = xsrc[v0.x * 4 + lane];
        acc[0] += c0 * bflo(a.x);
        acc[1] += c0 * bfhi(a.x);
        acc[2] += c0 * bflo(a.y);
        acc[3] += c0 * bfhi(a.y);
        acc[4] += c0 * bflo(a.z);
        acc[5] += c0 * bfhi(a.z);
        acc[6] += c0 * bflo(a.w);
        acc[7] += c0 * bfhi(a.w);
    }
    int node = bin * 64 + nl;
    if (node < N_NODES) {
        int4 o;
        o.x = (int)f2bf(acc[0]) | ((int)f2bf(acc[1]) << 16);
        o.y = (int)f2bf(acc[2]) | ((int)f2bf(acc[3]) << 16);
        o.z = (int)f2bf(acc[4]) | ((int)f2bf(acc[5]) << 16);
        o.w = (int)f2bf(acc[6]) | ((int)f2bf(acc[7]) << 16);
        outp[node * 4 + lane] = o;
    }
}

// 4. Dense epilogue via bf16 MFMA. x staged from the bf16 xsb copy (raw
// int4, L2-hot) -- bit-identical to converting fp32 x here.
// Per block: C[64 x 128 (z|h)] = A[64x96]_bf16 x B[96x128]_bf16 + bias.
// A-frag: A[m=lane&15][k=quad*8+j]; B-frag: B[k=quad*8+j][n=lane&15];
// C/D: col=lane&15, row=quad*4+reg (m89/m91-verified).
#define DN_GROUP 64
#define DN_BLOCKS ((N_NODES + DN_GROUP - 1) / DN_GROUP)  // 782
__global__ __launch_bounds__(256) void dense_kernel(
    const int4* __restrict__ xsb4,
    const int4* __restrict__ txo_b, const int4* __restrict__ txi_b,
    const unsigned short* __restrict__ wbf,
    const float* __restrict__ bz, const float* __restrict__ bh,
    const float* __restrict__ Wlin, const float* __restrict__ blin,
    float* __restrict__ out) {
    __shared__ unsigned short sA[64 * 104];  // 13.0 KB
    __shared__ unsigned short sB[12288];     // 24.0 KB

    int tid = threadIdx.x;
    int lane = tid & 63, w = tid >> 6;
    int lm = lane & 15, quad = lane >> 4;

    for (int idx = tid; idx < 3072; idx += 256)
        *(ushort4*)&sB[idx * 4] = ((const ushort4*)wbf)[idx];

    int node0 = blockIdx.x * DN_GROUP;
    // x part: 64 nodes x 4 int4 (bf16, raw copy from xsb)
    for (int idx = tid; idx < 64 * 4; idx += 256) {
        int nl = idx >> 2, q = idx & 3;
        int node = node0 + nl;
        int4 v = (node < N_NODES) ? xsb4[node * 4 + q] : make_int4(0, 0, 0, 0);
        *(int4*)&sA[nl * 104 + q * 8] = v;
    }
    // Tx part: 64 nodes x (4+4) int4 raw bf16
    for (int idx = tid; idx < 64 * 8; idx += 256) {
        int nl = idx >> 3, q = idx & 7;
        int node = node0 + nl;
        int4 v = make_int4(0, 0, 0, 0);
        if (node < N_NODES)
            v = (q < 4) ? txo_b[node * 4 + q] : txi_b[node * 4 + (q - 4)];
        *(int4*)&sA[nl * 104 + 32 + q * 8] = v;
    }

    float bzv[4], bhv[4], wlv[4];
#pragma unroll
    for (int bn = 0; bn < 4; ++bn) {
        int o = lm + 16 * bn;
        bzv[bn] = bz[o]; bhv[bn] = bh[o]; wlv[bn] = Wlin[o];
    }
    float bl = blin[0];
    __syncthreads();

    f32x4 acc[8];
#pragma unroll
    for (int bn = 0; bn < 4; ++bn) {
        acc[bn]     = (f32x4){bzv[bn], bzv[bn], bzv[bn], bzv[bn]};
        acc[bn + 4] = (f32x4){bhv[bn], bhv[bn], bhv[bn], bhv[bn]};
    }
#pragma unroll
    for (int kk = 0; kk < 3; ++kk) {
        bf16x8 af = *(const bf16x8*)&sA[(w * 16 + lm) * 104 + kk * 32 + quad * 8];
#pragma unroll
        for (int bn = 0; bn < 8; ++bn) {
            bf16x8 bf = *(const bf16x8*)&sB[((kk * 8 + bn) * 64 + lane) * 8];
            acc[bn] = __builtin_amdgcn_mfma_f32_16x16x32_bf16(af, bf, acc[bn], 0, 0, 0);
        }
    }

    float partial[4] = {0.f, 0.f, 0.f, 0.f};
#pragma unroll
    for (int bn = 0; bn < 4; ++bn) {
#pragma unroll
        for (int reg = 0; reg < 4; ++reg) {
            float az = acc[bn][reg], ah = acc[bn + 4][reg];
            float z = 1.f / (1.f + __expf(-az));
            float ht = 1.f - 2.f / (__expf(2.f * ah) + 1.f);
            partial[reg] += fmaxf((1.f - z) * ht, 0.f) * wlv[bn];
        }
    }
#pragma unroll
    for (int reg = 0; reg < 4; ++reg) {
        float s = partial[reg];
        s += __shfl_xor(s, 1, 64);
        s += __shfl_xor(s, 2, 64);
        s += __shfl_xor(s, 4, 64);
        s += __shfl_xor(s, 8, 64);
        if (lm == 0) {
            int node = node0 + w * 16 + quad * 4 + reg;
            if (node < N_NODES) out[node] = s + bl;
        }
    }
}

extern "C" void kernel_launch(void* const* d_in, const int* in_sizes, int n_in,
                              void* d_out, int out_size, void* d_ws, size_t ws_size,
                              hipStream_t stream) {
    const float* x = (const float*)d_in[0];
    const int* ei = (const int*)d_in[1];
    const float* ew = (const float*)d_in[2];
    const float* Wz = (const float*)d_in[3];
    const float* bz = (const float*)d_in[4];
    // d_in[5]=Wr, d_in[6]=br dead: H0==0 makes the reset gate a no-op
    const float* Wh = (const float*)d_in[7];
    const float* bh = (const float*)d_in[8];
    const float* Wlin = (const float*)d_in[9];
    const float* blin = (const float*)d_in[10];
    float* out = (float*)d_out;
    float* wf = (float*)d_ws;
    int* wi = (int*)d_ws;
    int2* binned = (int2*)(wi + WS_BINNED);

    // 0. fused prep: wprep + xconv + zero binTot
    prep_kernel<<<PREP_BLOCKS, 256, 0, stream>>>(
        Wz, Wh, (const float4*)x, (unsigned short*)(wi + WS_WBF),
        (ushort4*)(wi + WS_XSB), wi + WS_BINTOT);
    // 1. coalesced partition, both dirs per chunk, atomic slab reservation
    partition_kernel<<<NCHK, 512, 0, stream>>>(ei, ew, wi + WS_BINTOT, binned);
    // 2. per-bin degrees + node counts + pre-scaled rows (both dirs)
    bindeg_kernel<<<2 * NBIN, 256, 0, stream>>>(
        wi + WS_BINTOT, binned, (const float4*)x, wi + WS_BINCNT,
        (ushort4*)(wi + WS_XSO), (ushort4*)(wi + WS_XSI));
    // 3. fused binsort+gather, both dirs -> bf16 Tx_o / Tx_i
    fgather_kernel<<<2 * NBIN, 256, 0, stream>>>(
        (const int4*)(wi + WS_XSO), (const int4*)(wi + WS_XSI),
        wi + WS_BINTOT, wi + WS_BINCNT, binned, wf);
    // 4. MFMA dense epilogue (all-bf16 inputs)
    dense_kernel<<<DN_BLOCKS, 256, 0, stream>>>(
        (const int4*)(wi + WS_XSB), (const int4*)(wi + WS_TXO),
        (const int4*)(wi + WS_TXI), (const unsigned short*)(wi + WS_WBF),
        bz, bh, Wlin, blin, out);
}

// Round 10
// 168.006 us; speedup vs baseline: 1.0419x; 1.0419x over previous
//
#include <hip/hip_runtime.h>
#include <math.h>

#define N_NODES 50000
#define N_EDGES 1600000
#define IN_CH 32
#define HID 64

// ---------------- pipeline (5 dispatches) ----------------------------------
// prep(wprep+xconv+zero) -> partition(atomic slab reserve) -> bindeg(+row-
// scale) -> fgather -> dense(MFMA)
// Round-25: full revert to the R22 configuration (168.8us session best).
// A/B/C attribution across R22/R23/R24: split-dir partition (R22) beats the
// both-dirs-per-chunk merge (R24, +5us: doubled per-block scan/barrier
// chain, halved block parallelism) and the fgather+dense fusion (R23,
// +4us: cut gather residency 7->4 blocks/CU). All structural levers on
// this base are now individually falsified; this is the measured optimum.
#define NBIN 782
#define BIN_SHIFT 6
#define CHUNK 8192
#define NCHK ((N_EDGES + CHUNK - 1) / CHUNK)   // 196
#define FG_CAP 2560   // bin capacity: mean 2046 + ~11 sigma (Binomial)

#define PREP_WPREP_BLOCKS 48
#define PREP_XCONV_BLOCKS ((N_NODES * 8 + 255) / 256)  // 1563
#define PREP_BLOCKS (PREP_WPREP_BLOCKS + PREP_XCONV_BLOCKS + 1)  // 1612 (last zeroes binTot)

// ---------------- workspace layout (int element offsets into d_ws)
#define WS_WBF      0          // 6144 i = 12288 ushort (bf16 weights, B-frag order)
#define WS_BINTOT   6144       // 1568 i (per-(dir,bin) totals; atomic counters)
#define WS_BINCNT   7712       // 100096 i (1564 bins x 64 per-node counts)
#define WS_XSB      107808     // 800000 i = 1.6M ushort (bf16 x, unscaled)
#define WS_TXO      907808     // 800000 i (bf16 Tx_o, 50000 x 32)
#define WS_TXI      1707808    // 800000 i (bf16 Tx_i)
#define WS_XSO      2507808    // 800000 i (bf16 x*rdeg_out rows)
#define WS_XSI      3307808    // 800000 i (bf16 x*rdeg_in rows)
#define WS_BINNED   4107808    // int2[1564*2560] = 8007680 i (fixed slabs)
#define WS_END      12115488   // 48.5 MB (ws is 256 MiB)

typedef __attribute__((ext_vector_type(8))) short bf16x8;
typedef __attribute__((ext_vector_type(4))) float f32x4;

__device__ __forceinline__ unsigned short f2bf(float f) {  // RNE fp32 -> bf16
    unsigned int u = __float_as_uint(f);
    return (unsigned short)((u + 0x7fffu + ((u >> 16) & 1u)) >> 16);
}
__device__ __forceinline__ float bf2f(unsigned short b) {
    return __uint_as_float((unsigned int)b << 16);
}
// bf16-pair extraction from a packed 32-bit word (two channels)
__device__ __forceinline__ float bflo(int u) {
    return __uint_as_float(((unsigned int)u) << 16);
}
__device__ __forceinline__ float bfhi(int u) {
    return __uint_as_float(((unsigned int)u) & 0xffff0000u);
}

// 0. fused prep: block-role split.
//   blocks [0, 48)      : weight prep (bf16, B-fragment order)
//   blocks [48, 48+1563): x -> bf16 copy
//   block  1611         : zero binTot counters
// B-frag order: idx = ((kk*8+bn)*64+lane)*8+j holds
// Bmat[k=kk*32+(lane>>4)*8+j][n=bn*16+(lane&15)], Bmat = [Wz_eff | Wh_eff].
__global__ __launch_bounds__(256) void prep_kernel(
    const float* __restrict__ Wz, const float* __restrict__ Wh,
    const float4* __restrict__ x4, unsigned short* __restrict__ wbf,
    ushort4* __restrict__ xsb, int* __restrict__ binTot) {
    int tid = threadIdx.x;
    int b = blockIdx.x;
    if (b < PREP_WPREP_BLOCKS) {  // wprep role
        int idx = b * 256 + tid;
        if (idx >= 12288) return;
        int j = idx & 7, ln = (idx >> 3) & 63, bn = (idx >> 9) & 7, kk = idx >> 12;
        int k = kk * 32 + (ln >> 4) * 8 + j;
        int n = bn * 16 + (ln & 15);
        int slab = k >> 5, c = k & 31;
        const float* W = (n < 64) ? Wz : Wh;
        int o = n & 63;
        float v;
        if (slab == 0)      v = W[c * 64 + o] + W[(2 * 96 + c) * 64 + o];
        else if (slab == 1) v = W[(96 + c) * 64 + o];
        else                v = W[(3 * 96 + c) * 64 + o];
        wbf[idx] = f2bf(v);
    } else if (b < PREP_WPREP_BLOCKS + PREP_XCONV_BLOCKS) {  // xconv role
        int i = (b - PREP_WPREP_BLOCKS) * 256 + tid;
        if (i >= N_NODES * 8) return;
        float4 v = x4[i];
        ushort4 o;
        o.x = f2bf(v.x); o.y = f2bf(v.y); o.z = f2bf(v.z); o.w = f2bf(v.w);
        xsb[i] = o;
    } else {  // zero role (binTot atomic counters)
        for (int i = tid; i < 1568; i += 256) binTot[i] = 0;
    }
}

// 1. COALESCED partition with atomic slab reservation. One block = one
// (dir, chunk of 8192). Local LDS hist + rank -> one global atomicAdd per
// nonzero bin reserves a contiguous range in the bin's fixed slab
// (bin*FG_CAP); LDS re-staging keeps global write-out coalesced (~10.4-edge
// runs). Payload: dstLocal[21:16] | src[15:0] (bin stripped at write).
__global__ __launch_bounds__(512) void partition_kernel(
    const int* __restrict__ ei, const float* __restrict__ ew,
    int* __restrict__ binTot, int2* __restrict__ binned) {
    __shared__ int2 stg[CHUNK];      // 64 KB
    __shared__ int hist[NBIN];
    __shared__ int lst[NBIN];        // local bin starts (staging)
    __shared__ int gBase[NBIN];      // global base within slab (atomic)
    __shared__ int sc[512];
    int tid = threadIdx.x;
    int dir = (blockIdx.x >= NCHK) ? 1 : 0;
    int chunk = blockIdx.x - dir * NCHK;

    for (int i = tid; i < NBIN; i += 512) hist[i] = 0;
    __syncthreads();

    int e0 = chunk * CHUNK;
    int n_e = min(CHUNK, N_EDGES - e0);
    int binv[16], rankv[16];
    int2 pay[16];
#pragma unroll
    for (int j = 0; j < 16; ++j) {
        int idx = tid + j * 512;
        if (idx < n_e) {
            int e = e0 + idx;
            int r = ei[e];
            int c = ei[N_EDGES + e];
            int dst = dir ? r : c;
            int src = dir ? c : r;
            int b = dst >> BIN_SHIFT;
            binv[j] = b;
            rankv[j] = atomicAdd(&hist[b], 1);
            pay[j] = make_int2((int)(((unsigned)b << 22) | ((unsigned)(dst & 63) << 16) |
                                     (unsigned)src),
                               __float_as_int(ew[e]));
        } else {
            binv[j] = -1;
        }
    }
    __syncthreads();
    // pair-scan: 391 pairs cover 782 bins (staging offsets only)
    int ps = (tid < 391) ? (hist[2 * tid] + hist[2 * tid + 1]) : 0;
    sc[tid] = ps;
    __syncthreads();
    for (int off = 1; off < 512; off <<= 1) {
        int u = (tid >= off) ? sc[tid - off] : 0;
        __syncthreads();
        sc[tid] += u;
        __syncthreads();
    }
    if (tid < 391) {
        int pref = sc[tid] - ps;  // exclusive pair prefix
        lst[2 * tid] = pref;
        lst[2 * tid + 1] = pref + hist[2 * tid];
    }
    // reserve global ranges: one atomicAdd per nonzero bin
    for (int i = tid; i < NBIN; i += 512)
        gBase[i] = (hist[i] > 0) ? atomicAdd(&binTot[dir * NBIN + i], hist[i]) : 0;
    __syncthreads();
#pragma unroll
    for (int j = 0; j < 16; ++j)
        if (binv[j] >= 0) stg[lst[binv[j]] + rankv[j]] = pay[j];
    __syncthreads();
    for (int p = tid; p < n_e; p += 512) {
        int2 v2 = stg[p];
        int b = (int)(((unsigned)v2.x) >> 22);
        int off = gBase[b] + (p - lst[b]);
        if (off < FG_CAP)
            binned[(dir * NBIN + b) * FG_CAP + off] =
                make_int2(v2.x & 0x3FFFFF, v2.y);
    }
}

// 2. per-bin degrees + per-node counts + ROW SCALING.
// dir1 block computes rdeg_out for its 64 nodes -> writes xs_o = bf16(x *
// rdeg_out); dir0 block computes rdeg_in -> xs_i. Coalesced 8KB read + 4KB
// write per block. Bin slabs are fixed-stride (b*FG_CAP, count binTot[b]).
__global__ __launch_bounds__(256) void bindeg_kernel(
    const int* __restrict__ binTot, const int2* __restrict__ binned,
    const float4* __restrict__ x4, int* __restrict__ binCnt,
    ushort4* __restrict__ xso, ushort4* __restrict__ xsi) {
    __shared__ float wsum[64];
    __shared__ int cnt[64];
    int tid = threadIdx.x;
    int b = blockIdx.x;
    int dir = (b >= NBIN) ? 1 : 0;
    if (tid < 64) { wsum[tid] = 0.f; cnt[tid] = 0; }
    __syncthreads();
    int lo = b * FG_CAP;
    int n_e = min(binTot[b], FG_CAP);
    for (int p = tid; p < n_e; p += 256) {
        int2 v = binned[lo + p];
        int d = v.x >> 16;  // dstLocal (6 bits; bin bits stripped by partition)
        atomicAdd(&cnt[d], 1);
        atomicAdd(&wsum[d], __int_as_float(v.y));
    }
    __syncthreads();
    if (tid < 64) {
        binCnt[b * 64 + tid] = cnt[tid];
        float s = wsum[tid];
        wsum[tid] = (s != 0.f) ? (1.f / s) : 0.f;  // reuse slot: reciprocal
    }
    __syncthreads();
    // row scaling: 64 nodes x 8 float4 = 512 elements, 2 per thread
    ushort4* xsd = dir ? xso : xsi;  // dir1: rdeg_out -> xs_o; dir0: -> xs_i
    int node0 = (b - dir * NBIN) * 64;
#pragma unroll
    for (int i = tid; i < 512; i += 256) {
        int nl = i >> 3, q = i & 7;
        int node = node0 + nl;
        if (node < N_NODES) {
            float4 v = x4[node * 8 + q];
            float r = wsum[nl];
            ushort4 o;
            o.x = f2bf(v.x * r); o.y = f2bf(v.y * r);
            o.z = f2bf(v.z * r); o.w = f2bf(v.w * r);
            xsd[node * 8 + q] = o;
        }
    }
}

// 3. fused in-LDS binsort + register gather, both dirs, 256-thr blocks.
// B: 8-deep batched coalesced slab loads; atomic-rank; scatter (src, w).
// C: 64 groups x 4 lanes, int4 (16B, 8ch) gathers from PRE-SCALED rows.
__global__ __launch_bounds__(256, 7) void fgather_kernel(
    const int4* __restrict__ xso4, const int4* __restrict__ xsi4,
    const int* __restrict__ binTot, const int* __restrict__ binCnt,
    const int2* __restrict__ binned, float* __restrict__ ws_f) {
    __shared__ int2 s_edge[FG_CAP];  // 20.5 KB -> 7 blocks/CU
    __shared__ int s_off[65];
    __shared__ int s_cur[64];
    __shared__ int sc[64];
    int tid = threadIdx.x;
    int b = blockIdx.x;
    int dir = (b >= NBIN) ? 1 : 0;
    int bin = b - dir * NBIN;

    // A: exclusive scan of 64 counts
    int v = (tid < 64) ? binCnt[b * 64 + tid] : 0;
    if (tid < 64) sc[tid] = v;
    __syncthreads();
    for (int off = 1; off < 64; off <<= 1) {
        int u = (tid < 64 && tid >= off) ? sc[tid - off] : 0;
        __syncthreads();
        if (tid < 64) sc[tid] += u;
        __syncthreads();
    }
    if (tid < 64) {
        s_off[tid] = sc[tid] - v;
        s_cur[tid] = sc[tid] - v;
    }
    if (tid == 63) s_off[64] = sc[63];
    __syncthreads();

    // B: stream slab edges (8-deep batched); atomic-rank; scatter (src, w)
    int n_e = min(binTot[b], FG_CAP);
    const int2* bb = binned + b * FG_CAP;
    for (int base = 0; base < n_e; base += 2048) {
        int2 ev[8];
#pragma unroll
        for (int j = 0; j < 8; ++j) {
            int idx = base + j * 256 + tid;
            if (idx < n_e) ev[j] = bb[idx];
        }
#pragma unroll
        for (int j = 0; j < 8; ++j) {
            int idx = base + j * 256 + tid;
            if (idx < n_e) {
                int rk = atomicAdd(&s_cur[ev[j].x >> 16], 1);
                if (rk < FG_CAP)
                    s_edge[rk] = make_int2(ev[j].x & 0xffff, ev[j].y);
            }
        }
    }
    __syncthreads();

    // C: register-accumulating gather, 4 lanes/node, 16B loads, 4-way unrolled
    const int4* xsrc = dir ? xsi4 : xso4;  // dir0 uses x*rdeg_out rows
    int4* outp = (int4*)(ws_f + (dir == 0 ? WS_TXO : WS_TXI));
    int lane = tid & 3;        // which int4 (8 channels) of the 32-ch row
    int nl = tid >> 2;         // node-local index 0..63 (all nodes in one pass)
    int p = s_off[nl], end = s_off[nl + 1];
    float acc[8];
#pragma unroll
    for (int j = 0; j < 8; ++j) acc[j] = 0.f;
    for (; p + 3 < end; p += 4) {
        int2 v0 = s_edge[p], v1 = s_edge[p + 1];
        int2 v2 = s_edge[p + 2], v3 = s_edge[p + 3];
        int4 a0 = xsrc[v0.x * 4 + lane];
        int4 a1 = xsrc[v1.x * 4 + lane];
        int4 a2 = xsrc[v2.x * 4 + lane];
        int4 a3 = xsrc[v3.x * 4 + lane];
        float c0 = __int_as_float(v0.y), c1 = __int_as_float(v1.y);
        float c2 = __int_as_float(v2.y), c3 = __int_as_float(v3.y);
        acc[0] += c0 * bflo(a0.x) + c1 * bflo(a1.x) + c2 * bflo(a2.x) + c3 * bflo(a3.x);
        acc[1] += c0 * bfhi(a0.x) + c1 * bfhi(a1.x) + c2 * bfhi(a2.x) + c3 * bfhi(a3.x);
        acc[2] += c0 * bflo(a0.y) + c1 * bflo(a1.y) + c2 * bflo(a2.y) + c3 * bflo(a3.y);
        acc[3] += c0 * bfhi(a0.y) + c1 * bfhi(a1.y) + c2 * bfhi(a2.y) + c3 * bfhi(a3.y);
        acc[4] += c0 * bflo(a0.z) + c1 * bflo(a1.z) + c2 * bflo(a2.z) + c3 * bflo(a3.z);
        acc[5] += c0 * bfhi(a0.z) + c1 * bfhi(a1.z) + c2 * bfhi(a2.z) + c3 * bfhi(a3.z);
        acc[6] += c0 * bflo(a0.w) + c1 * bflo(a1.w) + c2 * bflo(a2.w) + c3 * bflo(a3.w);
        acc[7] += c0 * bfhi(a0.w) + c1 * bfhi(a1.w) + c2 * bfhi(a2.w) + c3 * bfhi(a3.w);
    }
    for (; p < end; ++p) {
        int2 v0 = s_edge[p];
        float c0 = __int_as_float(v0.y);
        int4 a = xsrc[v0.x * 4 + lane];
        acc[0] += c0 * bflo(a.x);
        acc[1] += c0 * bfhi(a.x);
        acc[2] += c0 * bflo(a.y);
        acc[3] += c0 * bfhi(a.y);
        acc[4] += c0 * bflo(a.z);
        acc[5] += c0 * bfhi(a.z);
        acc[6] += c0 * bflo(a.w);
        acc[7] += c0 * bfhi(a.w);
    }
    int node = bin * 64 + nl;
    if (node < N_NODES) {
        int4 o;
        o.x = (int)f2bf(acc[0]) | ((int)f2bf(acc[1]) << 16);
        o.y = (int)f2bf(acc[2]) | ((int)f2bf(acc[3]) << 16);
        o.z = (int)f2bf(acc[4]) | ((int)f2bf(acc[5]) << 16);
        o.w = (int)f2bf(acc[6]) | ((int)f2bf(acc[7]) << 16);
        outp[node * 4 + lane] = o;
    }
}

// 4. Dense epilogue via bf16 MFMA. x staged from the bf16 xsb copy (raw
// int4, L2-hot) -- bit-identical to converting fp32 x here.
// Per block: C[64 x 128 (z|h)] = A[64x96]_bf16 x B[96x128]_bf16 + bias.
// A-frag: A[m=lane&15][k=quad*8+j]; B-frag: B[k=quad*8+j][n=lane&15];
// C/D: col=lane&15, row=quad*4+reg (m89/m91-verified).
#define DN_GROUP 64
#define DN_BLOCKS ((N_NODES + DN_GROUP - 1) / DN_GROUP)  // 782
__global__ __launch_bounds__(256) void dense_kernel(
    const int4* __restrict__ xsb4,
    const int4* __restrict__ txo_b, const int4* __restrict__ txi_b,
    const unsigned short* __restrict__ wbf,
    const float* __restrict__ bz, const float* __restrict__ bh,
    const float* __restrict__ Wlin, const float* __restrict__ blin,
    float* __restrict__ out) {
    __shared__ unsigned short sA[64 * 104];  // 13.0 KB
    __shared__ unsigned short sB[12288];     // 24.0 KB

    int tid = threadIdx.x;
    int lane = tid & 63, w = tid >> 6;
    int lm = lane & 15, quad = lane >> 4;

    for (int idx = tid; idx < 3072; idx += 256)
        *(ushort4*)&sB[idx * 4] = ((const ushort4*)wbf)[idx];

    int node0 = blockIdx.x * DN_GROUP;
    // x part: 64 nodes x 4 int4 (bf16, raw copy from xsb)
    for (int idx = tid; idx < 64 * 4; idx += 256) {
        int nl = idx >> 2, q = idx & 3;
        int node = node0 + nl;
        int4 v = (node < N_NODES) ? xsb4[node * 4 + q] : make_int4(0, 0, 0, 0);
        *(int4*)&sA[nl * 104 + q * 8] = v;
    }
    // Tx part: 64 nodes x (4+4) int4 raw bf16
    for (int idx = tid; idx < 64 * 8; idx += 256) {
        int nl = idx >> 3, q = idx & 7;
        int node = node0 + nl;
        int4 v = make_int4(0, 0, 0, 0);
        if (node < N_NODES)
            v = (q < 4) ? txo_b[node * 4 + q] : txi_b[node * 4 + (q - 4)];
        *(int4*)&sA[nl * 104 + 32 + q * 8] = v;
    }

    float bzv[4], bhv[4], wlv[4];
#pragma unroll
    for (int bn = 0; bn < 4; ++bn) {
        int o = lm + 16 * bn;
        bzv[bn] = bz[o]; bhv[bn] = bh[o]; wlv[bn] = Wlin[o];
    }
    float bl = blin[0];
    __syncthreads();

    f32x4 acc[8];
#pragma unroll
    for (int bn = 0; bn < 4; ++bn) {
        acc[bn]     = (f32x4){bzv[bn], bzv[bn], bzv[bn], bzv[bn]};
        acc[bn + 4] = (f32x4){bhv[bn], bhv[bn], bhv[bn], bhv[bn]};
    }
#pragma unroll
    for (int kk = 0; kk < 3; ++kk) {
        bf16x8 af = *(const bf16x8*)&sA[(w * 16 + lm) * 104 + kk * 32 + quad * 8];
#pragma unroll
        for (int bn = 0; bn < 8; ++bn) {
            bf16x8 bf = *(const bf16x8*)&sB[((kk * 8 + bn) * 64 + lane) * 8];
            acc[bn] = __builtin_amdgcn_mfma_f32_16x16x32_bf16(af, bf, acc[bn], 0, 0, 0);
        }
    }

    float partial[4] = {0.f, 0.f, 0.f, 0.f};
#pragma unroll
    for (int bn = 0; bn < 4; ++bn) {
#pragma unroll
        for (int reg = 0; reg < 4; ++reg) {
            float az = acc[bn][reg], ah = acc[bn + 4][reg];
            float z = 1.f / (1.f + __expf(-az));
            float ht = 1.f - 2.f / (__expf(2.f * ah) + 1.f);
            partial[reg] += fmaxf((1.f - z) * ht, 0.f) * wlv[bn];
        }
    }
#pragma unroll
    for (int reg = 0; reg < 4; ++reg) {
        float s = partial[reg];
        s += __shfl_xor(s, 1, 64);
        s += __shfl_xor(s, 2, 64);
        s += __shfl_xor(s, 4, 64);
        s += __shfl_xor(s, 8, 64);
        if (lm == 0) {
            int node = node0 + w * 16 + quad * 4 + reg;
            if (node < N_NODES) out[node] = s + bl;
        }
    }
}

extern "C" void kernel_launch(void* const* d_in, const int* in_sizes, int n_in,
                              void* d_out, int out_size, void* d_ws, size_t ws_size,
                              hipStream_t stream) {
    const float* x = (const float*)d_in[0];
    const int* ei = (const int*)d_in[1];
    const float* ew = (const float*)d_in[2];
    const float* Wz = (const float*)d_in[3];
    const float* bz = (const float*)d_in[4];
    // d_in[5]=Wr, d_in[6]=br dead: H0==0 makes the reset gate a no-op
    const float* Wh = (const float*)d_in[7];
    const float* bh = (const float*)d_in[8];
    const float* Wlin = (const float*)d_in[9];
    const float* blin = (const float*)d_in[10];
    float* out = (float*)d_out;
    float* wf = (float*)d_ws;
    int* wi = (int*)d_ws;
    int2* binned = (int2*)(wi + WS_BINNED);

    // 0. fused prep: wprep + xconv + zero binTot
    prep_kernel<<<PREP_BLOCKS, 256, 0, stream>>>(
        Wz, Wh, (const float4*)x, (unsigned short*)(wi + WS_WBF),
        (ushort4*)(wi + WS_XSB), wi + WS_BINTOT);
    // 1. coalesced partition with atomic slab reservation
    partition_kernel<<<2 * NCHK, 512, 0, stream>>>(ei, ew, wi + WS_BINTOT, binned);
    // 2. per-bin degrees + node counts + pre-scaled rows (both dirs)
    bindeg_kernel<<<2 * NBIN, 256, 0, stream>>>(
        wi + WS_BINTOT, binned, (const float4*)x, wi + WS_BINCNT,
        (ushort4*)(wi + WS_XSO), (ushort4*)(wi + WS_XSI));
    // 3. fused binsort+gather, both dirs -> bf16 Tx_o / Tx_i
    fgather_kernel<<<2 * NBIN, 256, 0, stream>>>(
        (const int4*)(wi + WS_XSO), (const int4*)(wi + WS_XSI),
        wi + WS_BINTOT, wi + WS_BINCNT, binned, wf);
    // 4. MFMA dense epilogue (all-bf16 inputs)
    dense_kernel<<<DN_BLOCKS, 256, 0, stream>>>(
        (const int4*)(wi + WS_XSB), (const int4*)(wi + WS_TXO),
        (const int4*)(wi + WS_TXI), (const unsigned short*)(wi + WS_WBF),
        bz, bh, Wlin, blin, out);
}